// Round 11
// baseline (482.727 us; speedup 1.0000x reference)
//
#include <hip/hip_runtime.h>

// ---------- types ----------
typedef short short8 __attribute__((ext_vector_type(8)));   // 8 bf16 as i16
typedef float f32x4 __attribute__((ext_vector_type(4)));

#define GLOBAL_AS __attribute__((address_space(1)))
#define LDS_AS    __attribute__((address_space(3)))

__device__ __forceinline__ unsigned short f2bf(float f) {
    unsigned u = __builtin_bit_cast(unsigned, f);
    u += 0x7fffu + ((u >> 16) & 1u);          // round-to-nearest-even
    return (unsigned short)(u >> 16);
}

// ---------- convert kernels (memory-bound, vectorized) ----------
__global__ __launch_bounds__(256) void k_idx2bf(const int* __restrict__ idx,
                                                const float* __restrict__ cb,
                                                ushort* __restrict__ out, int n4) {
    int i = blockIdx.x * 256 + threadIdx.x;
    if (i >= n4) return;
    int4 v = reinterpret_cast<const int4*>(idx)[i];
    ushort4 o;
    o.x = f2bf(cb[v.x]); o.y = f2bf(cb[v.y]);
    o.z = f2bf(cb[v.z]); o.w = f2bf(cb[v.w]);
    reinterpret_cast<ushort4*>(out)[i] = o;
}

__global__ __launch_bounds__(256) void k_f2bf(const float* __restrict__ in,
                                              ushort* __restrict__ out, int n4) {
    int i = blockIdx.x * 256 + threadIdx.x;
    if (i >= n4) return;
    float4 v = reinterpret_cast<const float4*>(in)[i];
    ushort4 o;
    o.x = f2bf(v.x); o.y = f2bf(v.y); o.z = f2bf(v.z); o.w = f2bf(v.w);
    reinterpret_cast<ushort4*>(out)[i] = o;
}

// ---------- 256x256 bf16 gemm_bt: single-reg-set read-ahead pipeline ------
// 512 thr = 8 waves (2M x 4N), per-wave 128x64, BK=64, 2 K-tile LDS dbuf.
// READ-AHEAD VIA LIVENESS (no extra registers vs round 10):
//   ph1: read B1(t) into b1f (dead since prev ph4); stage AL(t+1)->nx;
//        barrier; lgkm(4) [drains A0,B0 read last ph4; leaves B1 in flight
//        under MFMA]; Q(0,0)=aF(A0)*b0f; barrier.
//   ph2: stage AE(t+2)->cur; barrier; lgkm(0) [B1 serviced under ph1 MFMA];
//        Q(0,1)=aF(A0)*b1f; then read A1(t) into aF (A0 dead); barrier.
//   ph3: stage BE(t+2)->cur; barrier; lgkm(0) [A1 residual small];
//        Q(1,0)=aF(A1)*b0f; vmcnt(8) [completes AE,BE(t+1)]; barrier.
//   ph4: read B0(t+1) into b0f (dead after ph3) -- rides under MFMA;
//        stage BL(t+2)->cur; barrier; lgkm(4) [no-wait]; Q(1,1)=aF(A1)*b1f;
//        then read A0(t+1) into aF (A1 dead) -- services under fence;
//        vmcnt(6); barrier.
// vm ledger/tile: 6 ->ph1 8 ->ph2 10 ->ph3 12 -vm8->8 ->ph4 10 -vm6-> 6.
// vm(8) completes oldest 4 = AE,BE(t+1) -> ph4's next-buf reads are safe
// (fence precedes a barrier -> all waves' copies complete). Region-reuse:
// every staged region's last ds_reads are behind a counted-lgkm + >=1
// barrier (AL(t+2) vs A1(t) reads: 2 barriers; AE(t+2) vs A0(t): 1; BE(t+2)
// vs B0(t): 1; BL(t+2) vs B1(t): 2). Tails: tile62 vm(4)@ph3, vm(0)@ph4;
// tile63 no stages/fences/pre-reads.
// Addressing: 4 base VGPRs (aB0/aB1/bB0/bB1 = LDS base + XOR-folded lane
// offset per k2) + compile-time ds imm <= 47104 < 64K (round 10's single
// base overflowed 16-bit imm for high lanes). Register ledger: 128 acc
// (AGPR) + 64 operands + ~16 addr = ~208 <= 256 at 8 waves/CU.
// Swizzle (0 conflicts, r3/r6-verified): linear LDS dest + pre-swizzled
// global col (slot s of row r holds s^(r&7)) + XOR-folded read offsets.

#define CH_AE(j) ((((j) & 8) << 1) | ((j) & 7))
#define CH_AL(j) (CH_AE(j) + 8)
#define CH_BE(j) ((((j) & 12) << 1) | ((j) & 3))
#define CH_BL(j) (CH_BE(j) + 4)

#define STAGE2(GB, LW, KB, CF) do {                                             \
    const int c0_ = CF(2 * w);                                                  \
    const int c1_ = CF(2 * w + 1);                                              \
    __builtin_amdgcn_global_load_lds(                                           \
        (const GLOBAL_AS void*)((GB) + (size_t)c0_ * 32768 + (KB)),             \
        (LDS_AS void*)((LW) + c0_ * 512), 16, 0, 0);                            \
    __builtin_amdgcn_global_load_lds(                                           \
        (const GLOBAL_AS void*)((GB) + (size_t)c1_ * 32768 + (KB)),             \
        (LDS_AS void*)((LW) + c1_ * 512), 16, 0, 0);                            \
} while (0)

// static-offset fragment reads: BUF/MH/NH literal tokens -> ds imm (<=47104)
#define READ_A(DST, BUF, MH) do {                                               \
    _Pragma("unroll")                                                           \
    for (int mi = 0; mi < 4; ++mi)                                              \
        DST[0][mi] = *reinterpret_cast<const short8*>(                          \
            aB0 + ((BUF) * 32768 + (MH) * 8192 + mi * 2048));                   \
    _Pragma("unroll")                                                           \
    for (int mi = 0; mi < 4; ++mi)                                              \
        DST[1][mi] = *reinterpret_cast<const short8*>(                          \
            aB1 + ((BUF) * 32768 + (MH) * 8192 + mi * 2048));                   \
} while (0)

#define READ_B(DST, BUF, NH) do {                                               \
    _Pragma("unroll")                                                           \
    for (int ni = 0; ni < 2; ++ni)                                              \
        DST[0][ni] = *reinterpret_cast<const short8*>(                          \
            bB0 + ((BUF) * 32768 + (NH) * 4096 + ni * 2048));                   \
    _Pragma("unroll")                                                           \
    for (int ni = 0; ni < 2; ++ni)                                              \
        DST[1][ni] = *reinterpret_cast<const short8*>(                          \
            bB1 + ((BUF) * 32768 + (NH) * 4096 + ni * 2048));                   \
} while (0)

#define MFMA16(MH, NH, AF, BF)                                                  \
    _Pragma("unroll")                                                           \
    for (int k2 = 0; k2 < 2; ++k2)                                              \
        _Pragma("unroll")                                                       \
        for (int mi = 0; mi < 4; ++mi)                                          \
            _Pragma("unroll")                                                   \
            for (int ni = 0; ni < 2; ++ni)                                      \
                acc[(MH) * 4 + mi][(NH) * 2 + ni] =                             \
                    __builtin_amdgcn_mfma_f32_16x16x32_bf16(                    \
                        AF[k2][mi], BF[k2][ni], acc[(MH) * 4 + mi][(NH) * 2 + ni], 0, 0, 0)

#define PHTOP do {                                                              \
    asm volatile("" ::: "memory");                                              \
    __builtin_amdgcn_s_barrier();                                               \
} while (0)

#define PHMIDN(N) do {                                                          \
    asm volatile("s_waitcnt lgkmcnt(" #N ")" ::: "memory");                     \
    __builtin_amdgcn_sched_barrier(0);                                          \
    __builtin_amdgcn_s_setprio(1);                                              \
} while (0)

#define PH_END do {                                                             \
    __builtin_amdgcn_s_setprio(0);                                              \
    asm volatile("" ::: "memory");                                              \
    __builtin_amdgcn_s_barrier();                                               \
    asm volatile("" ::: "memory");                                              \
} while (0)

// ph1: read B1(cur); stage; lgkm(4); Q(0,0)
#define PH1N(BUF, ...) do {                                                     \
    READ_B(b1f, BUF, 1);                                                        \
    __VA_ARGS__;                                                                \
    PHTOP; PHMIDN(4); MFMA16(0, 0, aF, b0f); PH_END;                            \
} while (0)

// ph2: stage; lgkm(0); Q(0,1); post-read A1(cur)
#define PH2N(BUF, ...) do {                                                     \
    __VA_ARGS__;                                                                \
    PHTOP; PHMIDN(0); MFMA16(0, 1, aF, b1f);                                    \
    __builtin_amdgcn_s_setprio(0);                                              \
    READ_A(aF, BUF, 1);                                                         \
    asm volatile("" ::: "memory");                                              \
    __builtin_amdgcn_s_barrier();                                               \
    asm volatile("" ::: "memory");                                              \
} while (0)

// ph3: stage; lgkm(0); Q(1,0); vm fence; barrier
#define PH3N(FN, ...) do {                                                      \
    __VA_ARGS__;                                                                \
    PHTOP; PHMIDN(0); MFMA16(1, 0, aF, b0f);                                    \
    __builtin_amdgcn_s_setprio(0);                                              \
    asm volatile("s_waitcnt vmcnt(" #FN ")" ::: "memory");                      \
    __builtin_amdgcn_s_barrier();                                               \
    asm volatile("" ::: "memory");                                              \
} while (0)

#define PH3T(...) do {                                                          \
    __VA_ARGS__;                                                                \
    PHTOP; PHMIDN(0); MFMA16(1, 0, aF, b0f); PH_END;                            \
} while (0)

// ph4: pre-read B0(next); stage; lgkm(4); Q(1,1); post-read A0(next); vm; bar
#define PH4N(NBUF, FN, ...) do {                                                \
    READ_B(b0f, NBUF, 0);                                                       \
    __VA_ARGS__;                                                                \
    PHTOP; PHMIDN(4); MFMA16(1, 1, aF, b1f);                                    \
    __builtin_amdgcn_s_setprio(0);                                              \
    READ_A(aF, NBUF, 0);                                                        \
    asm volatile("s_waitcnt vmcnt(" #FN ")" ::: "memory");                      \
    __builtin_amdgcn_s_barrier();                                               \
    asm volatile("" ::: "memory");                                              \
} while (0)

#define PH4T(...) do {                                                          \
    __VA_ARGS__;                                                                \
    PHTOP; PHMIDN(0); MFMA16(1, 1, aF, b1f); PH_END;                            \
} while (0)

// EPI=0: C=bf16, val = acc * extra[row]; EPI=1: C=f32, val = acc + extra[col]
template <int EPI>
__global__ __launch_bounds__(512, 2) void gemm256(const ushort* __restrict__ A,
                                                  const ushort* __restrict__ B,
                                                  void* __restrict__ C,
                                                  const float* __restrict__ extra) {
    constexpr int K = 4096, N = 4096;
    __shared__ ushort sA[2][256 * 64];
    __shared__ ushort sB[2][256 * 64];

    const int tid  = threadIdx.x;
    const int w    = tid >> 6;
    const int lane = tid & 63;
    const int wm = w >> 2, wn = w & 3;

    // XCD-aware swizzle (nwg % 8 == 0 for both grids)
    const int nwg = gridDim.x;
    const int sw  = ((int)blockIdx.x & 7) * (nwg >> 3) + ((int)blockIdx.x >> 3);
    const int m0 = (sw >> 4) * 256;      // 16 tiles per N-row (N=4096)
    const int n0 = (sw & 15) * 256;

    // staging bases: lane geometry folded once (global col pre-swizzled:
    // slot (lane&7) of row (lane>>3 mod 8) holds logical slot (lane&7)^(lane>>3))
    const int srow8 = lane >> 3;
    const int scol  = (((lane & 7) ^ (lane >> 3)) * 8);   // ushorts
    const ushort* gAl = A + (size_t)m0 * K + srow8 * 4096 + scol;
    const ushort* gBl = B + (size_t)n0 * K + srow8 * 4096 + scol;

    // fragment geometry (16x16x32: row=lane&15, k=(lane>>4)*8)
    const int fr   = lane & 15;
    const int fkb  = ((lane >> 4) & 3) * 16;          // byte offset along K
    const int swb  = (fr & 7) << 4;                   // read-side slot XOR
    const int arow = wm * 128 + fr;
    const int brow = wn * 64 + fr;
    // per-k2 base pointers with XOR-folded lane offsets (ds imm stays <64K)
    const char* aB0 = (const char*)&sA[0][0] + ((arow * 128 + 0  + fkb) ^ swb);
    const char* aB1 = (const char*)&sA[0][0] + ((arow * 128 + 64 + fkb) ^ swb);
    const char* bB0 = (const char*)&sB[0][0] + ((brow * 128 + 0  + fkb) ^ swb);
    const char* bB1 = (const char*)&sB[0][0] + ((brow * 128 + 64 + fkb) ^ swb);

    f32x4 acc[8][4];
#pragma unroll
    for (int i = 0; i < 8; ++i)
#pragma unroll
        for (int j = 0; j < 4; ++j) acc[i][j] = (f32x4){0.f, 0.f, 0.f, 0.f};

    short8 aF[2][4], b0f[2][2], b1f[2][2];

    // ---- prologue: stage t0 (AE,BE,BL,AL) + t1 (AE,BE,BL) = 14 loads ----
    STAGE2(gAl, sA[0], 0, CH_AE); STAGE2(gBl, sB[0], 0, CH_BE);
    STAGE2(gBl, sB[0], 0, CH_BL); STAGE2(gAl, sA[0], 0, CH_AL);
    STAGE2(gAl, sA[1], 64, CH_AE); STAGE2(gBl, sB[1], 64, CH_BE);
    STAGE2(gBl, sB[1], 64, CH_BL);
    asm volatile("s_waitcnt vmcnt(6)" ::: "memory");   // tile0 fully resident
    __builtin_amdgcn_s_barrier();
    asm volatile("" ::: "memory");
    READ_A(aF, 0, 0); READ_B(b0f, 0, 0);   // "ph4(-1)" reads (12, drained ph1)

    // ---- steady pairs: tiles 0..61 ----
    for (int pr = 0; pr < 31; ++pr) {
        const int t = 2 * pr;
        const int kb1 = (t + 1) * 64, kb2 = (t + 2) * 64, kb3 = (t + 3) * 64;
        // even tile t (buf0)
        PH1N(0,    STAGE2(gAl, sA[1], kb1, CH_AL));
        PH2N(0,    STAGE2(gAl, sA[0], kb2, CH_AE));
        PH3N(8,    STAGE2(gBl, sB[0], kb2, CH_BE));
        PH4N(1, 6, STAGE2(gBl, sB[0], kb2, CH_BL));
        // odd tile t+1 (buf1)
        PH1N(1,    STAGE2(gAl, sA[0], kb2, CH_AL));
        PH2N(1,    STAGE2(gAl, sA[1], kb3, CH_AE));
        PH3N(8,    STAGE2(gBl, sB[1], kb3, CH_BE));
        PH4N(0, 6, STAGE2(gBl, sB[1], kb3, CH_BL));
    }
    {   // ---- tail: tile 62 (buf0): stage only AL(63) ----
        PH1N(0,    STAGE2(gAl, sA[1], 63 * 64, CH_AL));
        PH2N(0,    ((void)0));
        PH3N(4,    ((void)0));
        PH4N(1, 0, ((void)0));
        // ---- tail: tile 63 (buf1): no stages, no fences, no pre-reads ----
        PH1N(1,    ((void)0));
        PH2N(1,    ((void)0));
        PH3T(((void)0));
        PH4T(((void)0));
    }

    // ---- epilogue: C/D layout col=lane&15, row=(lane>>4)*4+reg ----
    const int rb = m0 + wm * 128 + ((lane >> 4) * 4);
    const int cb = n0 + wn * 64 + (lane & 15);
    if (EPI == 0) {
        ushort* Cw = (ushort*)C;
#pragma unroll
        for (int mi = 0; mi < 8; ++mi) {
#pragma unroll
            for (int r = 0; r < 4; ++r) {
                const int row = rb + mi * 16 + r;
                const float s = extra[row];
#pragma unroll
                for (int ni = 0; ni < 4; ++ni)
                    Cw[(size_t)row * N + cb + ni * 16] = f2bf(acc[mi][ni][r] * s);
            }
        }
    } else {
        float* Cf = (float*)C;
#pragma unroll
        for (int ni = 0; ni < 4; ++ni) {
            const float b = extra[cb + ni * 16];
#pragma unroll
            for (int mi = 0; mi < 8; ++mi) {
#pragma unroll
                for (int r = 0; r < 4; ++r) {
                    const int row = rb + mi * 16 + r;
                    Cf[(size_t)row * N + cb + ni * 16] = acc[mi][ni][r] + b;
                }
            }
        }
    }
}

// ---------- launch ----------
extern "C" void kernel_launch(void* const* d_in, const int* in_sizes, int n_in,
                              void* d_out, int out_size, void* d_ws, size_t ws_size,
                              hipStream_t stream) {
    const float* x     = (const float*)d_in[0];   // (4,2048,4096) f32
    const int*   widx  = (const int*)  d_in[1];   // (4096,4096) i32
    const float* wscal = (const float*)d_in[2];   // (4096,)
    const float* bias  = (const float*)d_in[3];   // (4096,)
    const float* rot   = (const float*)d_in[4];   // (4096,4096) f32
    const float* cb    = (const float*)d_in[5];   // (16,)
    float* out = (float*)d_out;                   // (4,2048,4096) f32

    constexpr size_t IN_F = 4096, OUT_F = 4096, MTOK = 8192;
    char* ws = (char*)d_ws;
    ushort* wq   = (ushort*)(ws);                 // 32 MiB: codebook[idx] bf16
    ushort* rbuf = (ushort*)(ws + 33554432);      // 32 MiB: rotation bf16
    ushort* xb   = (ushort*)(ws + 67108864);      // 64 MiB: x bf16
    ushort* wb   = (ushort*)(ws + 134217728);     // 32 MiB: dequantized W bf16
    (void)ws_size; (void)in_sizes; (void)n_in; (void)out_size;

    // converts (memory-bound)
    {
        int n4 = (int)(OUT_F * IN_F / 4);
        k_idx2bf<<<n4 / 256, 256, 0, stream>>>(widx, cb, wq, n4);
        k_f2bf<<<n4 / 256, 256, 0, stream>>>(rot, rbuf, n4);
        int n4x = (int)(MTOK * IN_F / 4);
        k_f2bf<<<n4x / 256, 256, 0, stream>>>(x, xb, n4x);
    }

    // GEMM A: W[o,j] = scale[o] * sum_i Wq[o,i] R[j,i]   (M=4096 -> 256 wgs)
    gemm256<0><<<dim3(256), 512, 0, stream>>>(wq, rbuf, (void*)wb, wscal);

    // GEMM B: out[m,o] = sum_j x[m,j] W[o,j] + bias[o]   (M=8192 -> 512 wgs)
    gemm256<1><<<dim3(512), 512, 0, stream>>>(xb, wb, (void*)out, bias);
}

// Round 12
// 452.283 us; speedup vs baseline: 1.0673x; 1.0673x over previous
//
#include <hip/hip_runtime.h>

// ---------- types ----------
typedef short short8 __attribute__((ext_vector_type(8)));   // 8 bf16 as i16
typedef float f32x4 __attribute__((ext_vector_type(4)));

#define GLOBAL_AS __attribute__((address_space(1)))
#define LDS_AS    __attribute__((address_space(3)))

__device__ __forceinline__ unsigned short f2bf(float f) {
    unsigned u = __builtin_bit_cast(unsigned, f);
    u += 0x7fffu + ((u >> 16) & 1u);          // round-to-nearest-even
    return (unsigned short)(u >> 16);
}

// ---------- convert kernels (memory-bound, vectorized) ----------
__global__ __launch_bounds__(256) void k_idx2bf(const int* __restrict__ idx,
                                                const float* __restrict__ cb,
                                                ushort* __restrict__ out, int n4) {
    int i = blockIdx.x * 256 + threadIdx.x;
    if (i >= n4) return;
    int4 v = reinterpret_cast<const int4*>(idx)[i];
    ushort4 o;
    o.x = f2bf(cb[v.x]); o.y = f2bf(cb[v.y]);
    o.z = f2bf(cb[v.z]); o.w = f2bf(cb[v.w]);
    reinterpret_cast<ushort4*>(out)[i] = o;
}

__global__ __launch_bounds__(256) void k_f2bf(const float* __restrict__ in,
                                              ushort* __restrict__ out, int n4) {
    int i = blockIdx.x * 256 + threadIdx.x;
    if (i >= n4) return;
    float4 v = reinterpret_cast<const float4*>(in)[i];
    ushort4 o;
    o.x = f2bf(v.x); o.y = f2bf(v.y); o.z = f2bf(v.z); o.w = f2bf(v.w);
    reinterpret_cast<ushort4*>(out)[i] = o;
}

// ---------- 256x256 bf16 gemm_bt: round-10 schedule + split lgkm waits ----
// 512 thr = 8 waves (2M x 4N), per-wave 128x64, BK=64, 2 K-tile LDS dbuf.
// = round 10 (best measured: 45.5% MfmaUtil) with ONE change: the per-phase
// monolithic lgkmcnt(0)->16xMFMA is split so MFMAs begin as soon as their
// fragments land (DS completes in-order; counted lgkm per m201 pattern):
//   ph1 reads B0(4)+A0(8): lgkm(6)->4 MFMA (mi0-1,k2=0) -> lgkm(4)->4
//       (mi2-3,k2=0) -> lgkm(0)->8 (k2=1)
//   ph2 reads B1(4):       lgkm(2)->8 (k2=0) -> lgkm(0)->8 (k2=1)
//   ph3 reads A1(8):       lgkm(4)->8 (k2=0) -> lgkm(0)->8 (k2=1)
//   ph4 reads none:        16 MFMA straight (operands drained in ph3)
// Remaining LDS service overlaps the running MFMA stream instead of
// serializing ahead of it (round 10: 2304 cyc service + 2484 cyc MFMA
// serial = measured 5062 cyc/tile). No register delta, no schedule delta.
// Stages (tile t, cur=t&1): ph1 AL(t+1)->buf[cur^1]; ph2 AE(t+2), ph3
// BE(t+2), ph4 BL(t+2) -> buf[cur]; vmcnt(6) at ph4 end (completes tile
// t+1, leaves {AE,BE,BL}(t+2) in flight). Tails: tile62 vm(0)@ph4; tile63
// no stages/fences. Race-safety per region as verified in r6/r10.
// Swizzle (0 conflicts, r3/r6-verified): linear LDS dest + pre-swizzled
// global col (slot s of row r holds s^(r&7)) + XOR-folded read offsets.

#define CH_AE(j) ((((j) & 8) << 1) | ((j) & 7))
#define CH_AL(j) (CH_AE(j) + 8)
#define CH_BE(j) ((((j) & 12) << 1) | ((j) & 3))
#define CH_BL(j) (CH_BE(j) + 4)

#define STAGE2(GB, LW, KB, CF) do {                                             \
    const int c0_ = CF(2 * w);                                                  \
    const int c1_ = CF(2 * w + 1);                                              \
    __builtin_amdgcn_global_load_lds(                                           \
        (const GLOBAL_AS void*)((GB) + (size_t)c0_ * 32768 + (KB)),             \
        (LDS_AS void*)((LW) + c0_ * 512), 16, 0, 0);                            \
    __builtin_amdgcn_global_load_lds(                                           \
        (const GLOBAL_AS void*)((GB) + (size_t)c1_ * 32768 + (KB)),             \
        (LDS_AS void*)((LW) + c1_ * 512), 16, 0, 0);                            \
} while (0)

// static-offset fragment reads (k2-major issue order): BUF/MH/NH literals
#define READ_A(DST, BUF, MH) do {                                               \
    _Pragma("unroll")                                                           \
    for (int mi = 0; mi < 4; ++mi)                                              \
        DST[0][mi] = *reinterpret_cast<const short8*>(                          \
            sAc + ak0 + ((BUF) * 32768 + (MH) * 8192 + mi * 2048));             \
    _Pragma("unroll")                                                           \
    for (int mi = 0; mi < 4; ++mi)                                              \
        DST[1][mi] = *reinterpret_cast<const short8*>(                          \
            sAc + ak1 + ((BUF) * 32768 + (MH) * 8192 + mi * 2048));             \
} while (0)

// A-read variant interleaved for ph1 split: k2=0 mi0..3 then k2=1 mi0..3
// (same as READ_A; kept for clarity)

#define READ_B(DST, BUF, NH) do {                                               \
    _Pragma("unroll")                                                           \
    for (int ni = 0; ni < 2; ++ni)                                              \
        DST[0][ni] = *reinterpret_cast<const short8*>(                          \
            sBc + bk0 + ((BUF) * 32768 + (NH) * 4096 + ni * 2048));             \
    _Pragma("unroll")                                                           \
    for (int ni = 0; ni < 2; ++ni)                                              \
        DST[1][ni] = *reinterpret_cast<const short8*>(                          \
            sBc + bk1 + ((BUF) * 32768 + (NH) * 4096 + ni * 2048));             \
} while (0)

// MFMA sub-cluster: quadrant (MH,NH), k-half K2, rows MI_B..MI_E-1
#define MFMA_Q(MH, NH, K2, MI_B, MI_E, BF)                                      \
    _Pragma("unroll")                                                           \
    for (int mi = (MI_B); mi < (MI_E); ++mi)                                    \
        _Pragma("unroll")                                                       \
        for (int ni = 0; ni < 2; ++ni)                                          \
            acc[(MH) * 4 + mi][(NH) * 2 + ni] =                                 \
                __builtin_amdgcn_mfma_f32_16x16x32_bf16(                        \
                    aF[K2][mi], BF[K2][ni], acc[(MH) * 4 + mi][(NH) * 2 + ni], 0, 0, 0)

#define LG(N) do {                                                              \
    asm volatile("s_waitcnt lgkmcnt(" #N ")" ::: "memory");                     \
    __builtin_amdgcn_sched_barrier(0);                                          \
} while (0)

#define PHTOP do {                                                              \
    asm volatile("" ::: "memory");                                              \
    __builtin_amdgcn_s_barrier();                                               \
} while (0)

#define PH_END do {                                                             \
    __builtin_amdgcn_s_setprio(0);                                              \
    asm volatile("" ::: "memory");                                              \
    __builtin_amdgcn_s_barrier();                                               \
    asm volatile("" ::: "memory");                                              \
} while (0)

// ph1: reads B0(4)+A0(8); stage; barrier; split waits 6/4/0
#define PH1S(BUF, ...) do {                                                     \
    READ_B(b0f, BUF, 0); READ_A(aF, BUF, 0);                                    \
    __VA_ARGS__;                                                                \
    PHTOP;                                                                      \
    LG(6); __builtin_amdgcn_s_setprio(1);                                       \
    MFMA_Q(0, 0, 0, 0, 2, b0f);                                                 \
    LG(4);                                                                      \
    MFMA_Q(0, 0, 0, 2, 4, b0f);                                                 \
    LG(0);                                                                      \
    MFMA_Q(0, 0, 1, 0, 4, b0f);                                                 \
    PH_END;                                                                     \
} while (0)

// ph2: reads B1(4); stage; barrier; split waits 2/0
#define PH2S(BUF, ...) do {                                                     \
    READ_B(b1f, BUF, 1);                                                        \
    __VA_ARGS__;                                                                \
    PHTOP;                                                                      \
    LG(2); __builtin_amdgcn_s_setprio(1);                                       \
    MFMA_Q(0, 1, 0, 0, 4, b1f);                                                 \
    LG(0);                                                                      \
    MFMA_Q(0, 1, 1, 0, 4, b1f);                                                 \
    PH_END;                                                                     \
} while (0)

// ph3: reads A1(8); stage; barrier; split waits 4/0
#define PH3S(BUF, ...) do {                                                     \
    READ_A(aF, BUF, 1);                                                         \
    __VA_ARGS__;                                                                \
    PHTOP;                                                                      \
    LG(4); __builtin_amdgcn_s_setprio(1);                                       \
    MFMA_Q(1, 0, 0, 0, 4, b0f);                                                 \
    LG(0);                                                                      \
    MFMA_Q(1, 0, 1, 0, 4, b0f);                                                 \
    PH_END;                                                                     \
} while (0)

// ph4: no reads; 16 MFMA straight; vm fence; barrier
#define PH4S(FN, ...) do {                                                      \
    __VA_ARGS__;                                                                \
    PHTOP;                                                                      \
    __builtin_amdgcn_s_setprio(1);                                              \
    MFMA_Q(1, 1, 0, 0, 4, b1f);                                                 \
    MFMA_Q(1, 1, 1, 0, 4, b1f);                                                 \
    __builtin_amdgcn_s_setprio(0);                                              \
    asm volatile("s_waitcnt vmcnt(" #FN ")" ::: "memory");                      \
    __builtin_amdgcn_s_barrier();                                               \
    asm volatile("" ::: "memory");                                              \
} while (0)

#define PH4SNF(...) do {                                                        \
    __VA_ARGS__;                                                                \
    PHTOP;                                                                      \
    __builtin_amdgcn_s_setprio(1);                                              \
    MFMA_Q(1, 1, 0, 0, 4, b1f);                                                 \
    MFMA_Q(1, 1, 1, 0, 4, b1f);                                                 \
    PH_END;                                                                     \
} while (0)

// EPI=0: C=bf16, val = acc * extra[row]; EPI=1: C=f32, val = acc + extra[col]
template <int EPI>
__global__ __launch_bounds__(512, 2) void gemm256(const ushort* __restrict__ A,
                                                  const ushort* __restrict__ B,
                                                  void* __restrict__ C,
                                                  const float* __restrict__ extra) {
    constexpr int K = 4096, N = 4096;
    __shared__ ushort sA[2][256 * 64];
    __shared__ ushort sB[2][256 * 64];

    const int tid  = threadIdx.x;
    const int w    = tid >> 6;
    const int lane = tid & 63;
    const int wm = w >> 2, wn = w & 3;

    // XCD-aware swizzle (nwg % 8 == 0 for both grids)
    const int nwg = gridDim.x;
    const int sw  = ((int)blockIdx.x & 7) * (nwg >> 3) + ((int)blockIdx.x >> 3);
    const int m0 = (sw >> 4) * 256;      // 16 tiles per N-row (N=4096)
    const int n0 = (sw & 15) * 256;

    // staging bases: lane geometry folded once (global col pre-swizzled:
    // slot (lane&7) of row (lane>>3 mod 8) holds logical slot (lane&7)^(lane>>3))
    const int srow8 = lane >> 3;
    const int scol  = (((lane & 7) ^ (lane >> 3)) * 8);   // ushorts
    const ushort* gAl = A + (size_t)m0 * K + srow8 * 4096 + scol;
    const ushort* gBl = B + (size_t)n0 * K + srow8 * 4096 + scol;

    // fragment geometry (16x16x32: row=lane&15, k=(lane>>4)*8)
    const int fr   = lane & 15;
    const int fkb  = ((lane >> 4) & 3) * 16;          // byte offset along K
    const int swb  = (fr & 7) << 4;                   // read-side slot XOR
    const int arow = wm * 128 + fr;
    const int brow = wn * 64 + fr;
    // XOR-folded static read offsets (k2 folded pre-XOR; imms don't touch b4-6)
    const char* sAc = (const char*)&sA[0][0];
    const char* sBc = (const char*)&sB[0][0];
    const int ak0 = (arow * 128 + 0  + fkb) ^ swb;
    const int ak1 = (arow * 128 + 64 + fkb) ^ swb;
    const int bk0 = (brow * 128 + 0  + fkb) ^ swb;
    const int bk1 = (brow * 128 + 64 + fkb) ^ swb;

    f32x4 acc[8][4];
#pragma unroll
    for (int i = 0; i < 8; ++i)
#pragma unroll
        for (int j = 0; j < 4; ++j) acc[i][j] = (f32x4){0.f, 0.f, 0.f, 0.f};

    short8 aF[2][4], b0f[2][2], b1f[2][2];

    // ---- prologue: stage t0 (AE,BE,BL,AL) + t1 (AE,BE,BL) = 14 loads ----
    STAGE2(gAl, sA[0], 0, CH_AE); STAGE2(gBl, sB[0], 0, CH_BE);
    STAGE2(gBl, sB[0], 0, CH_BL); STAGE2(gAl, sA[0], 0, CH_AL);
    STAGE2(gAl, sA[1], 64, CH_AE); STAGE2(gBl, sB[1], 64, CH_BE);
    STAGE2(gBl, sB[1], 64, CH_BL);
    asm volatile("s_waitcnt vmcnt(6)" ::: "memory");   // tile0 fully resident
    __builtin_amdgcn_s_barrier();
    asm volatile("" ::: "memory");

    // ---- steady pairs: tiles 0..61 (stage refs <= tile 63) ----
    for (int pr = 0; pr < 31; ++pr) {
        const int t = 2 * pr;
        const int kb1 = (t + 1) * 64, kb2 = (t + 2) * 64, kb3 = (t + 3) * 64;
        // even tile t (buf0)
        PH1S(0, STAGE2(gAl, sA[1], kb1, CH_AL));
        PH2S(0, STAGE2(gAl, sA[0], kb2, CH_AE));
        PH3S(0, STAGE2(gBl, sB[0], kb2, CH_BE));
        PH4S(6, STAGE2(gBl, sB[0], kb2, CH_BL));
        // odd tile t+1 (buf1)
        PH1S(1, STAGE2(gAl, sA[0], kb2, CH_AL));
        PH2S(1, STAGE2(gAl, sA[1], kb3, CH_AE));
        PH3S(1, STAGE2(gBl, sB[1], kb3, CH_BE));
        PH4S(6, STAGE2(gBl, sB[1], kb3, CH_BL));
    }
    {   // ---- tail: tile 62 (buf0): stage only AL(63); drain at ph4 ----
        PH1S(0, STAGE2(gAl, sA[1], 63 * 64, CH_AL));
        PH2S(0, ((void)0));
        PH3S(0, ((void)0));
        PH4S(0, ((void)0));
        // ---- tail: tile 63 (buf1): no staging, no fence ----
        PH1S(1, ((void)0));
        PH2S(1, ((void)0));
        PH3S(1, ((void)0));
        PH4SNF(((void)0));
    }

    // ---- epilogue: C/D layout col=lane&15, row=(lane>>4)*4+reg ----
    const int rb = m0 + wm * 128 + ((lane >> 4) * 4);
    const int cb = n0 + wn * 64 + (lane & 15);
    if (EPI == 0) {
        ushort* Cw = (ushort*)C;
#pragma unroll
        for (int mi = 0; mi < 8; ++mi) {
#pragma unroll
            for (int r = 0; r < 4; ++r) {
                const int row = rb + mi * 16 + r;
                const float s = extra[row];
#pragma unroll
                for (int ni = 0; ni < 4; ++ni)
                    Cw[(size_t)row * N + cb + ni * 16] = f2bf(acc[mi][ni][r] * s);
            }
        }
    } else {
        float* Cf = (float*)C;
#pragma unroll
        for (int ni = 0; ni < 4; ++ni) {
            const float b = extra[cb + ni * 16];
#pragma unroll
            for (int mi = 0; mi < 8; ++mi) {
#pragma unroll
                for (int r = 0; r < 4; ++r) {
                    const int row = rb + mi * 16 + r;
                    Cf[(size_t)row * N + cb + ni * 16] = acc[mi][ni][r] + b;
                }
            }
        }
    }
}

// ---------- launch ----------
extern "C" void kernel_launch(void* const* d_in, const int* in_sizes, int n_in,
                              void* d_out, int out_size, void* d_ws, size_t ws_size,
                              hipStream_t stream) {
    const float* x     = (const float*)d_in[0];   // (4,2048,4096) f32
    const int*   widx  = (const int*)  d_in[1];   // (4096,4096) i32
    const float* wscal = (const float*)d_in[2];   // (4096,)
    const float* bias  = (const float*)d_in[3];   // (4096,)
    const float* rot   = (const float*)d_in[4];   // (4096,4096) f32
    const float* cb    = (const float*)d_in[5];   // (16,)
    float* out = (float*)d_out;                   // (4,2048,4096) f32

    constexpr size_t IN_F = 4096, OUT_F = 4096, MTOK = 8192;
    char* ws = (char*)d_ws;
    ushort* wq   = (ushort*)(ws);                 // 32 MiB: codebook[idx] bf16
    ushort* rbuf = (ushort*)(ws + 33554432);      // 32 MiB: rotation bf16
    ushort* xb   = (ushort*)(ws + 67108864);      // 64 MiB: x bf16
    ushort* wb   = (ushort*)(ws + 134217728);     // 32 MiB: dequantized W bf16
    (void)ws_size; (void)in_sizes; (void)n_in; (void)out_size;

    // converts (memory-bound)
    {
        int n4 = (int)(OUT_F * IN_F / 4);
        k_idx2bf<<<n4 / 256, 256, 0, stream>>>(widx, cb, wq, n4);
        k_f2bf<<<n4 / 256, 256, 0, stream>>>(rot, rbuf, n4);
        int n4x = (int)(MTOK * IN_F / 4);
        k_f2bf<<<n4x / 256, 256, 0, stream>>>(x, xb, n4x);
    }

    // GEMM A: W[o,j] = scale[o] * sum_i Wq[o,i] R[j,i]   (M=4096 -> 256 wgs)
    gemm256<0><<<dim3(256), 512, 0, stream>>>(wq, rbuf, (void*)wb, wscal);

    // GEMM B: out[m,o] = sum_j x[m,j] W[o,j] + bias[o]   (M=8192 -> 512 wgs)
    gemm256<1><<<dim3(512), 512, 0, stream>>>(xb, wb, (void*)out, bias);
}